// Round 10
// baseline (27.234 us; speedup 1.0000x reference)
//
#include <hip/hip_runtime.h>
#include <math.h>

#define LN2_INV  1.4426950408889634f   // 1/ln(2)
#define INV_2PI  0.15915494309189535f  // 1/(2*pi)
#define NH 32
// DIAGNOSTIC ROUND: exact round-8 kernel body, replicated 4x across the grid
// (rep 0 -> d_out, reps 1-3 -> disjoint d_ws regions or d_out fallback) so the
// dispatch exceeds the 40us poison-fills and lands in the rocprof top-5 with
// faithful counters. Math/layout identical to round 8 (passed, absmax 1.95e-3).

typedef float f32x16 __attribute__((ext_vector_type(16)));
typedef short bf16x8 __attribute__((ext_vector_type(8)));

__device__ __forceinline__ unsigned short bf16_rne(float x) {
    unsigned u = __float_as_uint(x);
    unsigned r = u + 0x7FFFu + ((u >> 16) & 1u);
    return (unsigned short)(r >> 16);
}
__device__ __forceinline__ float bf16f(unsigned short b) {
    return __uint_as_float(((unsigned)b) << 16);
}

__global__ __launch_bounds__(256, 2) void s4d_mfma_diag(
    const float* __restrict__ log_dt,
    const float* __restrict__ C,
    const float* __restrict__ log_A_real,
    const float* __restrict__ A_imag,
    float* __restrict__ o0, float* __restrict__ o1,
    float* __restrict__ o2, float* __restrict__ o3,
    int halfH)
{
    __shared__ float4 sC[2][NH][2];

    const int t    = threadIdx.x;
    const int rep  = blockIdx.x / halfH;
    const int bid  = blockIdx.x - rep * halfH;
    float* const obase = (rep == 0) ? o0 : (rep == 1) ? o1 : (rep == 2) ? o2 : o3;

    // ---- Phase A: per-(head,n) constants (threads 0..63, accurate libm) ----
    if (t < 2 * NH) {
        const int hl = t >> 5;
        const int n  = t & 31;
        const int h  = 2 * bid + hl;
        const float dt = expf(log_dt[h]);
        const float Ar = -expf(log_A_real[h * NH + n]);
        const float Ai = A_imag[h * NH + n];
        const float xr = Ar * dt;
        const float xi = Ai * dt;
        const float em = expf(xr);
        const float cs = cosf(xi);
        const float sn = sinf(xi);
        const float sr = em * cs;
        const float si = em * sn;
        const float er = sr - 1.0f;
        const float ei = si;
        const float inv = 1.0f / fmaf(Ar, Ar, Ai * Ai);
        const float tr = fmaf(er, Ar,  ei * Ai) * inv;
        const float ti = fmaf(ei, Ar, -er * Ai) * inv;
        const float c0 = C[(h * NH + n) * 2 + 0];
        const float c1 = C[(h * NH + n) * 2 + 1];
        const float cr = 2.0f * fmaf(c0, tr, -c1 * ti);
        const float ci = 2.0f * fmaf(c0, ti,  c1 * tr);
        const float e32 = expf(32.0f * xr);
        const float s32r = e32 * cosf(32.0f * xi);
        const float s32i = e32 * sinf(32.0f * xi);
        sC[hl][n][0] = make_float4(xr * LN2_INV, xi * INV_2PI, cr, ci);
        sC[hl][n][1] = make_float4(s32r, s32i, 0.0f, 0.0f);
    }
    __syncthreads();

    const int w    = t >> 6;
    const int hl   = w >> 1;
    const int R    = w & 1;
    const int h    = 2 * bid + hl;
    const int lane = t & 63;
    const int c    = lane & 31;
    const int hi   = lane >> 5;
    const float fa = (float)(64 * (R * 32 + c));
    const float fb = (float)c;

    f32x16 acc0, acc1;
#pragma unroll
    for (int i = 0; i < 16; ++i) { acc0[i] = 0.0f; acc1[i] = 0.0f; }

#pragma unroll
    for (int s = 0; s < 4; ++s) {
        const int nb = 8 * s + 4 * hi;
        float af[8], b0f[8], b1f[8];
#pragma unroll
        for (int j = 0; j < 4; ++j) {
            const int n = nb + j;
            const float4 q0 = sC[hl][n][0];
            const float4 q1 = sC[hl][n][1];
            const float eP  = __builtin_amdgcn_exp2f(q0.x * fa);
            const float thP = __builtin_amdgcn_fractf(q0.y * fa);
            const float kr  = eP * __builtin_amdgcn_cosf(thP);
            const float ki  = eP * __builtin_amdgcn_sinf(thP);
            af[2 * j + 0] = fmaf(q0.z, kr, -q0.w * ki);
            af[2 * j + 1] = fmaf(q0.z, ki,  q0.w * kr);
            const float eQ  = __builtin_amdgcn_exp2f(q0.x * fb);
            const float thQ = __builtin_amdgcn_fractf(q0.y * fb);
            const float qr  = eQ * __builtin_amdgcn_cosf(thQ);
            const float qi  = eQ * __builtin_amdgcn_sinf(thQ);
            b0f[2 * j + 0] = qr;
            b0f[2 * j + 1] = -qi;
            const float qr1 = fmaf(qr, q1.x, -qi * q1.y);
            const float qi1 = fmaf(qr, q1.y,  qi * q1.x);
            b1f[2 * j + 0] = qr1;
            b1f[2 * j + 1] = -qi1;
        }
        bf16x8 Ah, Al, B0h, B0l, B1h, B1l;
#pragma unroll
        for (int i = 0; i < 8; ++i) {
            const unsigned short ah = bf16_rne(af[i]);
            Ah[i] = (short)ah;
            Al[i] = (short)bf16_rne(af[i] - bf16f(ah));
            const unsigned short b0 = bf16_rne(b0f[i]);
            B0h[i] = (short)b0;
            B0l[i] = (short)bf16_rne(b0f[i] - bf16f(b0));
            const unsigned short b1 = bf16_rne(b1f[i]);
            B1h[i] = (short)b1;
            B1l[i] = (short)bf16_rne(b1f[i] - bf16f(b1));
        }
        acc0 = __builtin_amdgcn_mfma_f32_32x32x16_bf16(Ah, B0h, acc0, 0, 0, 0);
        acc0 = __builtin_amdgcn_mfma_f32_32x32x16_bf16(Ah, B0l, acc0, 0, 0, 0);
        acc0 = __builtin_amdgcn_mfma_f32_32x32x16_bf16(Al, B0h, acc0, 0, 0, 0);
        acc1 = __builtin_amdgcn_mfma_f32_32x32x16_bf16(Ah, B1h, acc1, 0, 0, 0);
        acc1 = __builtin_amdgcn_mfma_f32_32x32x16_bf16(Ah, B1l, acc1, 0, 0, 0);
        acc1 = __builtin_amdgcn_mfma_f32_32x32x16_bf16(Al, B1h, acc1, 0, 0, 0);
    }

    float* op = obase + (size_t)h * 4096;
#pragma unroll
    for (int r = 0; r < 16; ++r) {
        const int row = (r & 3) + 8 * (r >> 2) + 4 * hi;
        const int a   = R * 32 + row;
        op[a * 64 + c]      = acc0[r];
        op[a * 64 + 32 + c] = acc1[r];
    }
}

extern "C" void kernel_launch(void* const* d_in, const int* in_sizes, int n_in,
                              void* d_out, int out_size, void* d_ws, size_t ws_size,
                              hipStream_t stream)
{
    const float* log_dt     = (const float*)d_in[0];
    const float* C          = (const float*)d_in[1];
    const float* log_A_real = (const float*)d_in[2];
    const float* A_imag     = (const float*)d_in[3];
    float* out = (float*)d_out;

    const int H     = in_sizes[0];      // 1024; L = 4096 = 64*64
    const int halfH = H / 2;
    const int REPS  = 4;

    // Replicas 1-3 write to disjoint d_ws regions if available, else benignly
    // re-write identical values to d_out (still deterministic & correct).
    const size_t obytes = (size_t)out_size * sizeof(float);
    float* o1 = out; float* o2 = out; float* o3 = out;
    if (ws_size >= 3 * obytes) {
        o1 = (float*)d_ws;
        o2 = o1 + out_size;
        o3 = o2 + out_size;
    }

    hipLaunchKernelGGL(s4d_mfma_diag, dim3(halfH * REPS), dim3(256), 0, stream,
                       log_dt, C, log_A_real, A_imag, out, o1, o2, o3, halfH);
}

// Round 11
// 14.877 us; speedup vs baseline: 1.8307x; 1.8307x over previous
//
#include <hip/hip_runtime.h>
#include <math.h>

#define LN2_INV  1.4426950408889634f   // 1/ln(2)
#define INV_2PI  0.15915494309189535f  // 1/(2*pi)
#define NH 32
// L = 4096 = 64*64, l = 64a + b.  Per head: out[a][b] = sum_{k=0}^{63} A[a][k]*B[k][b]
//   A[a][2n]=Pr[n][a], A[a][2n+1]=Pi[n][a],  P = 2*coef*S^(64a)
//   B[2n][b]=Qr[n][b], B[2n+1][b]=-Qi[n][b], Q = S^b,  S = exp(dtA)
// One block per head, 4 waves; wave w -> ONE 32x32 C-tile (R=w>>1, Cc=w&1).
// Operands built in registers (trans evals per lane), 3-product bf16 split,
// v_mfma_f32_32x32x16_bf16. Low VGPR (~1 acc + 4 frags) => 4 waves/SIMD
// (occupancy step at VGPR<=128, m69), 4 blocks/CU resident. K-mapping and
// C/D layout identical to round 8 (verified, absmax 1.95e-3).

typedef float f32x16 __attribute__((ext_vector_type(16)));
typedef short bf16x8 __attribute__((ext_vector_type(8)));

__device__ __forceinline__ unsigned short bf16_rne(float x) {
    unsigned u = __float_as_uint(x);
    unsigned r = u + 0x7FFFu + ((u >> 16) & 1u);
    return (unsigned short)(r >> 16);
}
__device__ __forceinline__ float bf16f(unsigned short b) {
    return __uint_as_float(((unsigned)b) << 16);
}

__global__ __launch_bounds__(256, 4) void s4d_mfma_t1(
    const float* __restrict__ log_dt,
    const float* __restrict__ C,
    const float* __restrict__ log_A_real,
    const float* __restrict__ A_imag,
    float* __restrict__ out)
{
    __shared__ float4 sC[NH];   // {log2|S|/step, rev/step, 2*coef_r, 2*coef_i}

    const int h = blockIdx.x;
    const int t = threadIdx.x;

    // ---- Phase A: per-n constants (accurate libm, lanes 0..31) ----
    if (t < NH) {
        const int n = t;
        const float dt = expf(log_dt[h]);
        const float Ar = -expf(log_A_real[h * NH + n]);
        const float Ai = A_imag[h * NH + n];
        const float xr = Ar * dt;            // Re(dtA)
        const float xi = Ai * dt;            // Im(dtA)
        const float em = expf(xr);
        const float cs = cosf(xi);
        const float sn = sinf(xi);
        const float sr = em * cs;            // Re(S)
        const float si = em * sn;            // Im(S)
        const float er = sr - 1.0f;          // S-1
        const float ei = si;
        const float inv = 1.0f / fmaf(Ar, Ar, Ai * Ai);
        const float tr = fmaf(er, Ar,  ei * Ai) * inv;   // (S-1)/A
        const float ti = fmaf(ei, Ar, -er * Ai) * inv;
        const float c0 = C[(h * NH + n) * 2 + 0];
        const float c1 = C[(h * NH + n) * 2 + 1];
        const float cr = 2.0f * fmaf(c0, tr, -c1 * ti);  // 2*coef_r
        const float ci = 2.0f * fmaf(c0, ti,  c1 * tr);  // 2*coef_i
        sC[n] = make_float4(xr * LN2_INV, xi * INV_2PI, cr, ci);
    }
    __syncthreads();

    // ---- wave -> one 32x32 C-tile ----
    const int w    = t >> 6;
    const int R    = w >> 1;        // row block
    const int Cc   = w & 1;         // col block
    const int lane = t & 63;
    const int c    = lane & 31;
    const int hi   = lane >> 5;
    const float fa = (float)(64 * (R * 32 + c));   // P exponent arg (row)
    const float fb = (float)(Cc * 32 + c);         // Q exponent arg (col)

    f32x16 acc;
#pragma unroll
    for (int i = 0; i < 16; ++i) acc[i] = 0.0f;

#pragma unroll
    for (int s = 0; s < 4; ++s) {
        const int nb = 8 * s + 4 * hi;
        bf16x8 Ah, Al, Bh, Bl;
#pragma unroll
        for (int j = 0; j < 4; ++j) {
            const int n = nb + j;
            const float4 q = sC[n];           // wave-uniform -> broadcast read
            // P = 2*coef * S^(64a)
            const float eP  = __builtin_amdgcn_exp2f(q.x * fa);
            const float thP = __builtin_amdgcn_fractf(q.y * fa);
            const float kr  = eP * __builtin_amdgcn_cosf(thP);
            const float ki  = eP * __builtin_amdgcn_sinf(thP);
            const float Pr  = fmaf(q.z, kr, -q.w * ki);
            const float Pi  = fmaf(q.z, ki,  q.w * kr);
            // Q = S^b  (store Qr, -Qi)
            const float eQ  = __builtin_amdgcn_exp2f(q.x * fb);
            const float thQ = __builtin_amdgcn_fractf(q.y * fb);
            const float Qr  = eQ * __builtin_amdgcn_cosf(thQ);
            const float Qmi = -(eQ * __builtin_amdgcn_sinf(thQ));
            // bf16 hi/lo splits, packed in place (k = 16s + 8hi + 2j (+1))
            const unsigned short prh = bf16_rne(Pr);
            const unsigned short pih = bf16_rne(Pi);
            Ah[2 * j + 0] = (short)prh;
            Ah[2 * j + 1] = (short)pih;
            Al[2 * j + 0] = (short)bf16_rne(Pr - bf16f(prh));
            Al[2 * j + 1] = (short)bf16_rne(Pi - bf16f(pih));
            const unsigned short qrh = bf16_rne(Qr);
            const unsigned short qih = bf16_rne(Qmi);
            Bh[2 * j + 0] = (short)qrh;
            Bh[2 * j + 1] = (short)qih;
            Bl[2 * j + 0] = (short)bf16_rne(Qr - bf16f(qrh));
            Bl[2 * j + 1] = (short)bf16_rne(Qmi - bf16f(qih));
        }
        acc = __builtin_amdgcn_mfma_f32_32x32x16_bf16(Ah, Bh, acc, 0, 0, 0);
        acc = __builtin_amdgcn_mfma_f32_32x32x16_bf16(Ah, Bl, acc, 0, 0, 0);
        acc = __builtin_amdgcn_mfma_f32_32x32x16_bf16(Al, Bh, acc, 0, 0, 0);
    }

    // ---- store: C/D layout col=lane&31, row=(r&3)+8*(r>>2)+4*(lane>>5) ----
    float* op = out + (size_t)h * 4096;
#pragma unroll
    for (int r = 0; r < 16; ++r) {
        const int row = (r & 3) + 8 * (r >> 2) + 4 * hi;
        const int a   = R * 32 + row;
        op[a * 64 + Cc * 32 + c] = acc[r];
    }
}

extern "C" void kernel_launch(void* const* d_in, const int* in_sizes, int n_in,
                              void* d_out, int out_size, void* d_ws, size_t ws_size,
                              hipStream_t stream)
{
    const float* log_dt     = (const float*)d_in[0];
    const float* C          = (const float*)d_in[1];
    const float* log_A_real = (const float*)d_in[2];
    const float* A_imag     = (const float*)d_in[3];
    float* out = (float*)d_out;

    const int H = in_sizes[0];          // 1024; L = out_size/H = 4096 = 64*64
    hipLaunchKernelGGL(s4d_mfma_t1, dim3(H), dim3(256), 0, stream,
                       log_dt, C, log_A_real, A_imag, out);
}

// Round 12
// 12.520 us; speedup vs baseline: 2.1752x; 1.1882x over previous
//
#include <hip/hip_runtime.h>
#include <math.h>

#define LN2_INV  1.4426950408889634f   // 1/ln(2)
#define INV_2PI  0.15915494309189535f  // 1/(2*pi)
#define NH 32
// L = 4096 = 64*64, l = 64a + b.  Per head: out[a][b] = sum_{k=0}^{63} A[a][k]*B[k][b]
//   A[a][2n]=Pr[n][a], A[a][2n+1]=Pi[n][a],  P = 2*coef*S^(64a)
//   B[2n][b]=Qr[n][b], B[2n+1][b]=-Qi[n][b], Q = S^b,  S = exp(dtA)
// == Re( sum_n 2*coef*S^(64a+b) )  (verified structure, rounds 8-11)
//
// Round-8 structure (512 blocks, 2 heads/block, wave -> 2 C-tiles, S^32 trick
// halves Q transcendentals) with the bf16 3-product split replaced by an
// FP16 3-product split: (_Float16) cvt is one full-rate v_cvt_f16_f32 vs
// ~9 insts for bf16-rne+pack; split precision improves (2^-22 vs 2^-16).
// v_mfma_f32_32x32x16_f16, same K-mapping and verified C/D store layout.

typedef float    f32x16 __attribute__((ext_vector_type(16)));
typedef _Float16 f16x8  __attribute__((ext_vector_type(8)));

__global__ __launch_bounds__(256, 2) void s4d_mfma_f16(
    const float* __restrict__ log_dt,
    const float* __restrict__ C,
    const float* __restrict__ log_A_real,
    const float* __restrict__ A_imag,
    float* __restrict__ out)
{
    // per-n consts for the block's 2 heads:
    // [0] = {log2|S|/step, rev/step, 2*coef_r, 2*coef_i}
    // [1] = {Re(S^32), Im(S^32), 0, 0}
    __shared__ float4 sC[2][NH][2];

    const int t   = threadIdx.x;
    const int bid = blockIdx.x;

    // ---- Phase A: per-(head,n) constants (threads 0..63, accurate libm) ----
    if (t < 2 * NH) {
        const int hl = t >> 5;
        const int n  = t & 31;
        const int h  = 2 * bid + hl;
        const float dt = expf(log_dt[h]);
        const float Ar = -expf(log_A_real[h * NH + n]);
        const float Ai = A_imag[h * NH + n];
        const float xr = Ar * dt;            // Re(dtA)
        const float xi = Ai * dt;            // Im(dtA)
        const float em = expf(xr);
        const float cs = cosf(xi);
        const float sn = sinf(xi);
        const float sr = em * cs;            // Re(S)
        const float si = em * sn;            // Im(S)
        const float er = sr - 1.0f;          // S-1
        const float ei = si;
        const float inv = 1.0f / fmaf(Ar, Ar, Ai * Ai);
        const float tr = fmaf(er, Ar,  ei * Ai) * inv;   // (S-1)/A
        const float ti = fmaf(ei, Ar, -er * Ai) * inv;
        const float c0 = C[(h * NH + n) * 2 + 0];
        const float c1 = C[(h * NH + n) * 2 + 1];
        const float cr = 2.0f * fmaf(c0, tr, -c1 * ti);  // 2*coef_r
        const float ci = 2.0f * fmaf(c0, ti,  c1 * tr);  // 2*coef_i
        const float e32  = expf(32.0f * xr);
        const float s32r = e32 * cosf(32.0f * xi);
        const float s32i = e32 * sinf(32.0f * xi);
        sC[hl][n][0] = make_float4(xr * LN2_INV, xi * INV_2PI, cr, ci);
        sC[hl][n][1] = make_float4(s32r, s32i, 0.0f, 0.0f);
    }
    __syncthreads();

    // ---- wave setup: wave w -> head hl=w>>1, row-block R=w&1 ----
    const int w    = t >> 6;
    const int hl   = w >> 1;
    const int R    = w & 1;
    const int h    = 2 * bid + hl;
    const int lane = t & 63;
    const int c    = lane & 31;     // A-row within block / B-col within block
    const int hi   = lane >> 5;     // lane half -> k-slot half
    const float fa = (float)(64 * (R * 32 + c));   // P exponent arg
    const float fb = (float)c;                     // Q exponent arg (col-block 0)

    f32x16 acc0, acc1;
#pragma unroll
    for (int i = 0; i < 16; ++i) { acc0[i] = 0.0f; acc1[i] = 0.0f; }

    // ---- 4 K-steps of 16 (k = 16s + 8*hi + slot; n = k>>1) ----
#pragma unroll
    for (int s = 0; s < 4; ++s) {
        const int nb = 8 * s + 4 * hi;
        float af[8], b0f[8], b1f[8];
#pragma unroll
        for (int j = 0; j < 4; ++j) {
            const int n = nb + j;
            const float4 q0 = sC[hl][n][0];   // ar1, ai1, cr, ci
            const float4 q1 = sC[hl][n][1];   // s32r, s32i
            // P = 2*coef * S^(64a)  (this lane's row)
            const float eP  = __builtin_amdgcn_exp2f(q0.x * fa);
            const float thP = __builtin_amdgcn_fractf(q0.y * fa);
            const float kr  = eP * __builtin_amdgcn_cosf(thP);
            const float ki  = eP * __builtin_amdgcn_sinf(thP);
            af[2 * j + 0] = fmaf(q0.z, kr, -q0.w * ki);   // Pr
            af[2 * j + 1] = fmaf(q0.z, ki,  q0.w * kr);   // Pi
            // Q = S^b for col-block 0; col-block 1 = Q * S^32
            const float eQ  = __builtin_amdgcn_exp2f(q0.x * fb);
            const float thQ = __builtin_amdgcn_fractf(q0.y * fb);
            const float qr  = eQ * __builtin_amdgcn_cosf(thQ);
            const float qi  = eQ * __builtin_amdgcn_sinf(thQ);
            b0f[2 * j + 0] = qr;
            b0f[2 * j + 1] = -qi;
            const float qr1 = fmaf(qr, q1.x, -qi * q1.y);
            const float qi1 = fmaf(qr, q1.y,  qi * q1.x);
            b1f[2 * j + 0] = qr1;
            b1f[2 * j + 1] = -qi1;
        }
        // fp16 hi/lo split (3-product emulation of fp32 matmul)
        f16x8 Ah, Al, B0h, B0l, B1h, B1l;
#pragma unroll
        for (int i = 0; i < 8; ++i) {
            const _Float16 ah = (_Float16)af[i];
            Ah[i] = ah;
            Al[i] = (_Float16)(af[i] - (float)ah);
            const _Float16 b0 = (_Float16)b0f[i];
            B0h[i] = b0;
            B0l[i] = (_Float16)(b0f[i] - (float)b0);
            const _Float16 b1 = (_Float16)b1f[i];
            B1h[i] = b1;
            B1l[i] = (_Float16)(b1f[i] - (float)b1);
        }
        acc0 = __builtin_amdgcn_mfma_f32_32x32x16_f16(Ah, B0h, acc0, 0, 0, 0);
        acc0 = __builtin_amdgcn_mfma_f32_32x32x16_f16(Ah, B0l, acc0, 0, 0, 0);
        acc0 = __builtin_amdgcn_mfma_f32_32x32x16_f16(Al, B0h, acc0, 0, 0, 0);
        acc1 = __builtin_amdgcn_mfma_f32_32x32x16_f16(Ah, B1h, acc1, 0, 0, 0);
        acc1 = __builtin_amdgcn_mfma_f32_32x32x16_f16(Ah, B1l, acc1, 0, 0, 0);
        acc1 = __builtin_amdgcn_mfma_f32_32x32x16_f16(Al, B1h, acc1, 0, 0, 0);
    }

    // ---- store: C/D layout col=lane&31, row=(r&3)+8*(r>>2)+4*(lane>>5) ----
    float* op = out + (size_t)h * 4096;
#pragma unroll
    for (int r = 0; r < 16; ++r) {
        const int row = (r & 3) + 8 * (r >> 2) + 4 * hi;
        const int a   = R * 32 + row;
        op[a * 64 + c]      = acc0[r];
        op[a * 64 + 32 + c] = acc1[r];
    }
}

extern "C" void kernel_launch(void* const* d_in, const int* in_sizes, int n_in,
                              void* d_out, int out_size, void* d_ws, size_t ws_size,
                              hipStream_t stream)
{
    const float* log_dt     = (const float*)d_in[0];
    const float* C          = (const float*)d_in[1];
    const float* log_A_real = (const float*)d_in[2];
    const float* A_imag     = (const float*)d_in[3];
    float* out = (float*)d_out;

    const int H = in_sizes[0];          // 1024; L = out_size/H = 4096 = 64*64
    hipLaunchKernelGGL(s4d_mfma_f16, dim3(H / 2), dim3(256), 0, stream,
                       log_dt, C, log_A_real, A_imag, out);
}